// Round 15
// baseline (308.347 us; speedup 1.0000x reference)
//
#include <hip/hip_runtime.h>
#include <hip/hip_bf16.h>

#define N_NODES 50000
#define N_EDGES 800000
#define DD 64
#define CAP 64
#define SCAN_BLOCKS ((N_NODES + 255) / 256)   // 196

// R1/R3: FP atomics op-rate-bound -> CSR+gather. R8-R12: random 256B-row
// READS capped ~2 TB/s (~30G lines/s), one read per row, no reuse -> ~90us
// floor for the f32 gather. R14: bucket CSR + d_out scratch -> 141us.
// R15: move randomness to the WRITE side and halve the lines: stream
// edge_attr sequentially, convert bf16, scatter-write 128B rows to exact CSR
// positions; aggregate becomes a per-node CONTIGUOUS bf16 read (~2KB/node).
// Host falls back to the R14 path if ws < ~103MB.
//
// big-ws layout: offs[50000] i32 | bsum[256] (+pad) | ebf[800000*32] u32
// small-ws layout: cnt[50000] i32 | slots[50000*64] i32

__device__ __forceinline__ float swish_f(float v) {
    return v / (1.0f + __expf(-v));
}

__device__ __forceinline__ float bf2f(unsigned int u) {
    return __uint_as_float(u << 16);
}

__global__ __launch_bounds__(256) void zero_kernel(int4* __restrict__ p, int n4)
{
    const int i = blockIdx.x * 256 + threadIdx.x;
    if (i < n4) p[i] = make_int4(0, 0, 0, 0);
}

// 4 edges per thread via int4 (N_EDGES % 4 == 0)
__global__ __launch_bounds__(256) void hist_kernel(
    const int* __restrict__ col, int* __restrict__ cnt)
{
    const int i = blockIdx.x * 256 + threadIdx.x;
    if (i < N_EDGES / 4) {
        const int4 c = reinterpret_cast<const int4*>(col)[i];
        atomicAdd(&cnt[c.x], 1);
        atomicAdd(&cnt[c.y], 1);
        atomicAdd(&cnt[c.z], 1);
        atomicAdd(&cnt[c.w], 1);
    }
}

__global__ __launch_bounds__(256) void scanA_kernel(
    int* __restrict__ offs, int* __restrict__ bsum)
{
    __shared__ int sm[256];
    const int t = threadIdx.x;
    const int idx = blockIdx.x * 256 + t;
    const int v = (idx < N_NODES) ? offs[idx] : 0;
    sm[t] = v;
    __syncthreads();
    #pragma unroll
    for (int d = 1; d < 256; d <<= 1) {
        const int w2 = (t >= d) ? sm[t - d] : 0;
        __syncthreads();
        sm[t] += w2;
        __syncthreads();
    }
    if (idx < N_NODES) offs[idx] = sm[t] - v;
    if (t == 255) bsum[blockIdx.x] = sm[255];
}

__global__ __launch_bounds__(256) void scanBC_kernel(
    int* __restrict__ offs, const int* __restrict__ bsum)
{
    __shared__ int sm[256];
    __shared__ int base;
    const int t = threadIdx.x;
    sm[t] = (t < SCAN_BLOCKS) ? bsum[t] : 0;
    __syncthreads();
    #pragma unroll
    for (int d = 1; d < 256; d <<= 1) {
        const int w2 = (t >= d) ? sm[t - d] : 0;
        __syncthreads();
        sm[t] += w2;
        __syncthreads();
    }
    if (t == 0) base = (blockIdx.x == 0) ? 0 : sm[blockIdx.x - 1];
    __syncthreads();
    const int idx = blockIdx.x * 256 + t;
    if (idx < N_NODES) offs[idx] += base;
}

// one WAVE per edge: sequential 256B f32 read, bf16 convert+pack,
// random 128B row write at CSR position. offs[n]: start(n) -> start(n+1).
__global__ __launch_bounds__(256) void scatter_cvt_kernel(
    const float* __restrict__ edge_attr,
    const int* __restrict__ col,
    int* __restrict__ offs,
    unsigned int* __restrict__ ebf)
{
    const int e = (blockIdx.x * 256 + threadIdx.x) >> 6;   // grid exact
    const int lane = threadIdx.x & 63;
    const int c = col[e];
    int pos;
    if (lane == 0) pos = atomicAdd(&offs[c], 1);
    pos = __shfl(pos, 0, 64);
    const float v = edge_attr[(size_t)e * DD + lane];
    // f32 -> bf16 RNE (inputs finite)
    const unsigned int b = __float_as_uint(v);
    const unsigned int r = (b + 0x7fffu + ((b >> 16) & 1u)) >> 16;
    const unsigned int lo = __shfl((int)r, 2 * (lane & 31), 64);
    const unsigned int hi = __shfl((int)r, 2 * (lane & 31) + 1, 64);
    if (lane < 32)
        ebf[(size_t)pos * 32 + lane] = (lo & 0xffffu) | (hi << 16);
}

// one wave per node: contiguous bf16 rows [beg,deg). Lane half covers rows
// i/i+1; 2 loads per iter (rows i..i+3) for ILP; xor-32 reduce; float2 store.
__global__ __launch_bounds__(256) void agg_seq_kernel(
    const unsigned int* __restrict__ ebf,
    const int* __restrict__ offs,
    float* __restrict__ agg)
{
    const int n = (blockIdx.x * 256 + threadIdx.x) >> 6;
    if (n >= N_NODES) return;
    const int lane = threadIdx.x & 63;
    const int half = lane >> 5;
    const int w32 = lane & 31;
    const int beg = (n == 0) ? 0 : offs[n - 1];
    const int deg = offs[n] - beg;

    float a0 = 0.f, a1 = 0.f;
    const size_t base = (size_t)beg * 32 + w32;
    for (int i = 0; i < deg; i += 4) {            // deg wave-uniform
        const int r0 = i + half;
        const int r1 = i + 2 + half;
        const unsigned int w0 = (r0 < deg) ? ebf[base + (size_t)r0 * 32] : 0u;
        const unsigned int w1 = (r1 < deg) ? ebf[base + (size_t)r1 * 32] : 0u;
        a0 += bf2f(w0 & 0xffffu) + bf2f(w1 & 0xffffu);
        a1 += bf2f(w0 >> 16) + bf2f(w1 >> 16);
    }
    a0 += __shfl_xor(a0, 32, 64);
    a1 += __shfl_xor(a1, 32, 64);
    if (lane < 32) {
        float2 o; o.x = a0; o.y = a1;
        *reinterpret_cast<float2*>(agg + (size_t)n * DD + 2 * w32) = o;
    }
}

// ---- R14 fallback path (small ws): bucket-append + random-row gather ----
__global__ __launch_bounds__(256) void fill_direct_kernel(
    const int* __restrict__ col, int* __restrict__ cnt, int* __restrict__ slots)
{
    const int i = blockIdx.x * 256 + threadIdx.x;
    if (i < N_EDGES / 4) {
        const int4 c = reinterpret_cast<const int4*>(col)[i];
        const int e = i * 4;
        int p;
        p = atomicAdd(&cnt[c.x], 1); if (p < CAP) slots[c.x * CAP + p] = e + 0;
        p = atomicAdd(&cnt[c.y], 1); if (p < CAP) slots[c.y * CAP + p] = e + 1;
        p = atomicAdd(&cnt[c.z], 1); if (p < CAP) slots[c.z * CAP + p] = e + 2;
        p = atomicAdd(&cnt[c.w], 1); if (p < CAP) slots[c.w * CAP + p] = e + 3;
    }
}

__global__ __launch_bounds__(256) void agg_kernel(
    const float* __restrict__ edge_attr,
    const int* __restrict__ cnt,
    const int* __restrict__ slots,
    float* __restrict__ agg)
{
    const int n = (blockIdx.x * 256 + threadIdx.x) >> 6;
    if (n >= N_NODES) return;
    const int lane = threadIdx.x & 63;
    const int q4 = (lane & 15) << 2;
    const int slot = lane >> 4;
    const int beg = n * CAP;
    const int deg = min(cnt[n], CAP);

    float4 acc = make_float4(0.f, 0.f, 0.f, 0.f);
    if (deg > 0) {
        const int qcnt  = (deg + 3) >> 2;
        const int s_beg = beg + slot * qcnt;
        const int s_end = min(beg + deg, s_beg + qcnt);
        const int last  = beg + deg - 1;
        const int s_lim = s_beg + qcnt;
        for (int i = s_beg; i < s_lim; i += 4) {
            const int i0 = min(i + 0, last);
            const int i1 = min(i + 1, last);
            const int i2 = min(i + 2, last);
            const int i3 = min(i + 3, last);
            const float m0 = (i + 0 < s_end) ? 1.f : 0.f;
            const float m1 = (i + 1 < s_end) ? 1.f : 0.f;
            const float m2 = (i + 2 < s_end) ? 1.f : 0.f;
            const float m3 = (i + 3 < s_end) ? 1.f : 0.f;
            const int e0 = slots[i0];
            const int e1 = slots[i1];
            const int e2 = slots[i2];
            const int e3 = slots[i3];
            const float4 v0 = *reinterpret_cast<const float4*>(edge_attr + (size_t)e0 * DD + q4);
            const float4 v1 = *reinterpret_cast<const float4*>(edge_attr + (size_t)e1 * DD + q4);
            const float4 v2 = *reinterpret_cast<const float4*>(edge_attr + (size_t)e2 * DD + q4);
            const float4 v3 = *reinterpret_cast<const float4*>(edge_attr + (size_t)e3 * DD + q4);
            acc.x += m0 * v0.x + m1 * v1.x + m2 * v2.x + m3 * v3.x;
            acc.y += m0 * v0.y + m1 * v1.y + m2 * v2.y + m3 * v3.y;
            acc.z += m0 * v0.z + m1 * v1.z + m2 * v2.z + m3 * v3.z;
            acc.w += m0 * v0.w + m1 * v1.w + m2 * v2.w + m3 * v3.w;
        }
    }
    #pragma unroll
    for (int m = 16; m < 64; m <<= 1) {
        acc.x += __shfl_xor(acc.x, m, 64);
        acc.y += __shfl_xor(acc.y, m, 64);
        acc.z += __shfl_xor(acc.z, m, 64);
        acc.w += __shfl_xor(acc.w, m, 64);
    }
    if (slot == 0)
        *reinterpret_cast<float4*>(agg + (size_t)n * DD + q4) = acc;
}

// ---------------- fused 2-layer MLP: 8 waves x 8 output dims ----------------
// agg aliases out (scratch): each thread reads only its own node's agg row,
// then writes that node's out row -> program-ordered, no __restrict__.
__global__ __launch_bounds__(512) void mlp_kernel(
    const float* __restrict__ x,
    const float* agg,
    const float* __restrict__ u,
    const int* __restrict__ batch,
    const float* __restrict__ W1,
    const float* __restrict__ b1,
    const float* __restrict__ W2,
    const float* __restrict__ b2,
    float* out)
{
    __shared__ float sh[64][65];
    const int lane = threadIdx.x & 63;
    const int j0 = __builtin_amdgcn_readfirstlane((threadIdx.x >> 6) << 3);
    const int node = blockIdx.x * 64 + lane;
    const bool valid = node < N_NODES;
    const int nc = valid ? node : (N_NODES - 1);

    float acc[8];
    #pragma unroll
    for (int j = 0; j < 8; ++j) acc[j] = b1[j0 + j];

    const float* row0 = x + (size_t)nc * DD;
    const float* row1 = agg + (size_t)nc * DD;
    const float* row2 = u + (size_t)batch[nc] * DD;

    #pragma unroll
    for (int s = 0; s < 3; ++s) {
        const float* row = (s == 0) ? row0 : (s == 1) ? row1 : row2;
        const float* w = W1 + (size_t)s * 64 * 64 + j0;
        for (int kk = 0; kk < 64; kk += 4) {
            const float4 v = *reinterpret_cast<const float4*>(row + kk);
            #pragma unroll
            for (int i = 0; i < 4; ++i) {
                const float iv = (i == 0) ? v.x : (i == 1) ? v.y : (i == 2) ? v.z : v.w;
                const float* wr = w + (size_t)(kk + i) * 64;
                #pragma unroll
                for (int j = 0; j < 8; ++j)
                    acc[j] += iv * wr[j];
            }
        }
    }

    #pragma unroll
    for (int j = 0; j < 8; ++j)
        sh[lane][j0 + j] = swish_f(acc[j]);

    __syncthreads();

    float acc2[8];
    #pragma unroll
    for (int j = 0; j < 8; ++j) acc2[j] = b2[j0 + j];
    for (int k = 0; k < 64; ++k) {
        const float hk = sh[lane][k];
        const float* wr = W2 + (size_t)k * 64 + j0;
        #pragma unroll
        for (int j = 0; j < 8; ++j)
            acc2[j] += hk * wr[j];
    }

    if (valid) {
        float* o = out + (size_t)node * DD + j0;
        #pragma unroll
        for (int j = 0; j < 8; j += 4) {
            float4 r;
            r.x = swish_f(acc2[j + 0]);
            r.y = swish_f(acc2[j + 1]);
            r.z = swish_f(acc2[j + 2]);
            r.w = swish_f(acc2[j + 3]);
            *reinterpret_cast<float4*>(o + j) = r;
        }
    }
}

extern "C" void kernel_launch(void* const* d_in, const int* in_sizes, int n_in,
                              void* d_out, int out_size, void* d_ws, size_t ws_size,
                              hipStream_t stream) {
    const float* x         = (const float*)d_in[0];
    const int*   ei        = (const int*)d_in[1];
    const float* edge_attr = (const float*)d_in[2];
    const float* u         = (const float*)d_in[3];
    const int*   batch     = (const int*)d_in[4];
    const float* W1        = (const float*)d_in[5];
    const float* b1        = (const float*)d_in[6];
    const float* W2        = (const float*)d_in[7];
    const float* b2        = (const float*)d_in[8];
    float* out = (float*)d_out;
    float* agg = out;                 // d_out doubles as agg scratch
    const int* col = ei + N_EDGES;    // edge_index[1]

    const size_t EBF_OFF = 201024;    // offs(200000) + bsum(1024), 16B-aligned
    const size_t NEED_BIG = EBF_OFF + (size_t)N_EDGES * 32 * sizeof(unsigned int);

    if (ws_size >= NEED_BIG) {
        int* offs = (int*)d_ws;
        int* bsum = offs + N_NODES;
        unsigned int* ebf = (unsigned int*)((char*)d_ws + EBF_OFF);

        zero_kernel<<<(12500 + 255) / 256, 256, 0, stream>>>((int4*)offs, 12500);
        hist_kernel<<<(N_EDGES / 4 + 255) / 256, 256, 0, stream>>>(col, offs);
        scanA_kernel<<<SCAN_BLOCKS, 256, 0, stream>>>(offs, bsum);
        scanBC_kernel<<<SCAN_BLOCKS, 256, 0, stream>>>(offs, bsum);
        scatter_cvt_kernel<<<N_EDGES / 4, 256, 0, stream>>>(edge_attr, col, offs, ebf);
        agg_seq_kernel<<<(N_NODES + 3) / 4, 256, 0, stream>>>(ebf, offs, agg);
        mlp_kernel<<<(N_NODES + 63) / 64, 512, 0, stream>>>(x, agg, u, batch, W1, b1, W2, b2, out);
    } else {
        // R14 fallback (13.1 MB)
        int* cnt   = (int*)d_ws;
        int* slots = cnt + N_NODES;

        zero_kernel<<<(12500 + 255) / 256, 256, 0, stream>>>((int4*)cnt, 12500);
        fill_direct_kernel<<<(N_EDGES / 4 + 255) / 256, 256, 0, stream>>>(col, cnt, slots);
        agg_kernel<<<(N_NODES + 3) / 4, 256, 0, stream>>>(edge_attr, cnt, slots, agg);
        mlp_kernel<<<(N_NODES + 63) / 64, 512, 0, stream>>>(x, agg, u, batch, W1, b1, W2, b2, out);
    }
}

// Round 16
// 131.917 us; speedup vs baseline: 2.3374x; 2.3374x over previous
//
#include <hip/hip_runtime.h>
#include <hip/hip_bf16.h>

#define N_NODES 50000
#define N_EDGES 800000
#define DD 64
#define CAP 64   // slots per node; deg ~ Poisson(16), P(deg>=64) < 1e-15

// Established by probes R1-R15:
//  - f32 scatter atomics: op-rate-bound, 75 G/s (R1/R3: 682us) -> use CSR/gather
//  - random 256B-row READS: ~2.3 TB/s effective, invariant across 4-row loads,
//    1-row loads, any ILP/TLP depth (R8/R9/R11/R12) -> gather ~90us floor
//  - random 128B WRITES: ~2x worse than reads (R15 scatter_cvt 230us) -> any
//    sort/partition scheme pays more than the direct gather
//  - fusion that cuts waves/CU loses (R8 node-serial, R11 64KB-LDS); fusion
//    that keeps waves is neutral (R10) -> keep agg/mlp separate
//  - cooperative launch at 256 blocks starves atomic TLP (R10: 190us CSR)
//  - bucket-append CSR (this file) beats exact hist+scan CSR by ~37us (R14)
// R14 = 141us ~= zero(3) + fill(25, atomic-rate) + gather(90, random-read cap)
//       + mlp(23, ~45% f32 VALU peak); graph-replay gaps ~0.
//
// ws layout: cnt[50000] i32 | slots[50000*64] i32  (~13 MB)

__device__ __forceinline__ float swish_f(float v) {
    return v / (1.0f + __expf(-v));
}

__global__ __launch_bounds__(256) void zero_kernel(int4* __restrict__ p, int n4)
{
    const int i = blockIdx.x * 256 + threadIdx.x;
    if (i < n4) p[i] = make_int4(0, 0, 0, 0);
}

// 4 edges per thread via int4; bucket-append (no hist/scan needed).
__global__ __launch_bounds__(256) void fill_direct_kernel(
    const int* __restrict__ col, int* __restrict__ cnt, int* __restrict__ slots)
{
    const int i = blockIdx.x * 256 + threadIdx.x;
    if (i < N_EDGES / 4) {
        const int4 c = reinterpret_cast<const int4*>(col)[i];
        const int e = i * 4;
        int p;
        p = atomicAdd(&cnt[c.x], 1); if (p < CAP) slots[c.x * CAP + p] = e + 0;
        p = atomicAdd(&cnt[c.y], 1); if (p < CAP) slots[c.y * CAP + p] = e + 1;
        p = atomicAdd(&cnt[c.z], 1); if (p < CAP) slots[c.z * CAP + p] = e + 2;
        p = atomicAdd(&cnt[c.w], 1); if (p < CAP) slots[c.w * CAP + p] = e + 3;
    }
}

// one wave per node: 16 dim-lanes x float4; slot s owns a contiguous quarter
// of the node's bucket; wave-uniform trip count; clamp+mask tail (R9).
__global__ __launch_bounds__(256) void agg_kernel(
    const float* __restrict__ edge_attr,
    const int* __restrict__ cnt,
    const int* __restrict__ slots,
    float* __restrict__ agg)
{
    const int n = (blockIdx.x * 256 + threadIdx.x) >> 6;
    if (n >= N_NODES) return;
    const int lane = threadIdx.x & 63;
    const int q4 = (lane & 15) << 2;  // dim offset
    const int slot = lane >> 4;       // quarter 0..3
    const int beg = n * CAP;
    const int deg = min(cnt[n], CAP);

    float4 acc = make_float4(0.f, 0.f, 0.f, 0.f);
    if (deg > 0) {                                   // wave-uniform
        const int qcnt  = (deg + 3) >> 2;
        const int s_beg = beg + slot * qcnt;
        const int s_end = min(beg + deg, s_beg + qcnt);
        const int last  = beg + deg - 1;
        const int s_lim = s_beg + qcnt;
        for (int i = s_beg; i < s_lim; i += 4) {
            const int i0 = min(i + 0, last);
            const int i1 = min(i + 1, last);
            const int i2 = min(i + 2, last);
            const int i3 = min(i + 3, last);
            const float m0 = (i + 0 < s_end) ? 1.f : 0.f;
            const float m1 = (i + 1 < s_end) ? 1.f : 0.f;
            const float m2 = (i + 2 < s_end) ? 1.f : 0.f;
            const float m3 = (i + 3 < s_end) ? 1.f : 0.f;
            const int e0 = slots[i0];
            const int e1 = slots[i1];
            const int e2 = slots[i2];
            const int e3 = slots[i3];
            const float4 v0 = *reinterpret_cast<const float4*>(edge_attr + (size_t)e0 * DD + q4);
            const float4 v1 = *reinterpret_cast<const float4*>(edge_attr + (size_t)e1 * DD + q4);
            const float4 v2 = *reinterpret_cast<const float4*>(edge_attr + (size_t)e2 * DD + q4);
            const float4 v3 = *reinterpret_cast<const float4*>(edge_attr + (size_t)e3 * DD + q4);
            acc.x += m0 * v0.x + m1 * v1.x + m2 * v2.x + m3 * v3.x;
            acc.y += m0 * v0.y + m1 * v1.y + m2 * v2.y + m3 * v3.y;
            acc.z += m0 * v0.z + m1 * v1.z + m2 * v2.z + m3 * v3.z;
            acc.w += m0 * v0.w + m1 * v1.w + m2 * v2.w + m3 * v3.w;
        }
    }
    #pragma unroll
    for (int m = 16; m < 64; m <<= 1) {
        acc.x += __shfl_xor(acc.x, m, 64);
        acc.y += __shfl_xor(acc.y, m, 64);
        acc.z += __shfl_xor(acc.z, m, 64);
        acc.w += __shfl_xor(acc.w, m, 64);
    }
    if (slot == 0)
        *reinterpret_cast<float4*>(agg + (size_t)n * DD + q4) = acc;
}

// ---------------- fused 2-layer MLP: 8 waves x 8 output dims ----------------
// agg aliases out (scratch): each thread reads only its own node's agg row,
// then writes that node's out row -> program-ordered, no __restrict__.
__global__ __launch_bounds__(512) void mlp_kernel(
    const float* __restrict__ x,
    const float* agg,
    const float* __restrict__ u,
    const int* __restrict__ batch,
    const float* __restrict__ W1,
    const float* __restrict__ b1,
    const float* __restrict__ W2,
    const float* __restrict__ b2,
    float* out)
{
    __shared__ float sh[64][65];
    const int lane = threadIdx.x & 63;
    const int j0 = __builtin_amdgcn_readfirstlane((threadIdx.x >> 6) << 3);
    const int node = blockIdx.x * 64 + lane;
    const bool valid = node < N_NODES;
    const int nc = valid ? node : (N_NODES - 1);

    float acc[8];
    #pragma unroll
    for (int j = 0; j < 8; ++j) acc[j] = b1[j0 + j];

    const float* row0 = x + (size_t)nc * DD;
    const float* row1 = agg + (size_t)nc * DD;
    const float* row2 = u + (size_t)batch[nc] * DD;

    #pragma unroll
    for (int s = 0; s < 3; ++s) {
        const float* row = (s == 0) ? row0 : (s == 1) ? row1 : row2;
        const float* w = W1 + (size_t)s * 64 * 64 + j0;
        for (int kk = 0; kk < 64; kk += 4) {
            const float4 v = *reinterpret_cast<const float4*>(row + kk);
            #pragma unroll
            for (int i = 0; i < 4; ++i) {
                const float iv = (i == 0) ? v.x : (i == 1) ? v.y : (i == 2) ? v.z : v.w;
                const float* wr = w + (size_t)(kk + i) * 64;
                #pragma unroll
                for (int j = 0; j < 8; ++j)
                    acc[j] += iv * wr[j];
            }
        }
    }

    #pragma unroll
    for (int j = 0; j < 8; ++j)
        sh[lane][j0 + j] = swish_f(acc[j]);

    __syncthreads();

    float acc2[8];
    #pragma unroll
    for (int j = 0; j < 8; ++j) acc2[j] = b2[j0 + j];
    for (int k = 0; k < 64; ++k) {
        const float hk = sh[lane][k];
        const float* wr = W2 + (size_t)k * 64 + j0;
        #pragma unroll
        for (int j = 0; j < 8; ++j)
            acc2[j] += hk * wr[j];
    }

    if (valid) {
        float* o = out + (size_t)node * DD + j0;
        #pragma unroll
        for (int j = 0; j < 8; j += 4) {
            float4 r;
            r.x = swish_f(acc2[j + 0]);
            r.y = swish_f(acc2[j + 1]);
            r.z = swish_f(acc2[j + 2]);
            r.w = swish_f(acc2[j + 3]);
            *reinterpret_cast<float4*>(o + j) = r;
        }
    }
}

extern "C" void kernel_launch(void* const* d_in, const int* in_sizes, int n_in,
                              void* d_out, int out_size, void* d_ws, size_t ws_size,
                              hipStream_t stream) {
    const float* x         = (const float*)d_in[0];
    const int*   ei        = (const int*)d_in[1];
    const float* edge_attr = (const float*)d_in[2];
    const float* u         = (const float*)d_in[3];
    const int*   batch     = (const int*)d_in[4];
    const float* W1        = (const float*)d_in[5];
    const float* b1        = (const float*)d_in[6];
    const float* W2        = (const float*)d_in[7];
    const float* b2        = (const float*)d_in[8];
    float* out = (float*)d_out;

    int* cnt   = (int*)d_ws;
    int* slots = cnt + N_NODES;
    float* agg = out;                 // d_out doubles as agg scratch
    const int* col = ei + N_EDGES;    // edge_index[1]

    zero_kernel<<<(12500 + 255) / 256, 256, 0, stream>>>((int4*)cnt, 12500);
    fill_direct_kernel<<<(N_EDGES / 4 + 255) / 256, 256, 0, stream>>>(col, cnt, slots);
    agg_kernel<<<(N_NODES + 3) / 4, 256, 0, stream>>>(edge_attr, cnt, slots, agg);
    mlp_kernel<<<(N_NODES + 63) / 64, 512, 0, stream>>>(x, agg, u, batch, W1, b1, W2, b2, out);
}